// Round 5
// baseline (232.563 us; speedup 1.0000x reference)
//
#include <hip/hip_runtime.h>
#include <math.h>

#define BATCH 8
#define CH    256
#define H     128
#define W     128
#define HW    (H * W)          // 16384
#define OH    65
#define OW    65
#define NPIX  (OH * OW)        // 4225

// ---------------- K1: channel L2 norms, streaming ----------------
// 256 blocks (1/CU) x 512 thr (8 waves). Block = one 512-pixel tile of one
// image, all 256 channels; wave wv covers channels [wv*32, wv*32+32).
// Per channel a wave reads 2 KB contiguous (2 x dwordx4/lane); 32 channels
// are independent -> deep load pipeline. One LDS tree at the end.
#define NTILE   512
#define K1_TPB  512
#define K1_CPW  32             // channels per wave

__global__ __launch_bounds__(K1_TPB) void norm_kernel(const float4* __restrict__ x4,
                                                      float* __restrict__ nrm) {
    const int tile = blockIdx.x;       // b*32 + t
    const int b    = tile >> 5;
    const int t    = tile & 31;
    const int lane = threadIdx.x & 63;
    const int wv   = threadIdx.x >> 6;

    const float4* p = x4 + (size_t)(b * CH + wv * K1_CPW) * (HW / 4)
                         + t * (NTILE / 4) + lane;
    float4 a0 = {0.f, 0.f, 0.f, 0.f}, a1 = {0.f, 0.f, 0.f, 0.f};
    #pragma unroll 8
    for (int c = 0; c < K1_CPW; ++c) {
        float4 v0 = p[(size_t)c * (HW / 4)];
        float4 v1 = p[(size_t)c * (HW / 4) + 64];
        a0.x += v0.x * v0.x; a0.y += v0.y * v0.y;
        a0.z += v0.z * v0.z; a0.w += v0.w * v0.w;
        a1.x += v1.x * v1.x; a1.y += v1.y * v1.y;
        a1.z += v1.z * v1.z; a1.w += v1.w * v1.w;
    }
    __shared__ float part[8][NTILE];   // 16 KB
    ((float4*)part[wv])[lane]      = a0;   // float4-slot lane   -> px 4*lane
    ((float4*)part[wv])[64 + lane] = a1;   // float4-slot 64+l   -> px 256+4*lane
    __syncthreads();

    // 512 threads: one pixel each, 8-way sum, sqrt, coalesced store
    float s = 0.f;
    #pragma unroll
    for (int w = 0; w < 8; ++w) s += part[w][threadIdx.x];
    nrm[(size_t)b * HW + t * NTILE + threadIdx.x] = sqrtf(s);
}

// ---------------- K2: softmax-weighted 3x3/s2 pooling ----------------
// Block = (image b, 8-channel group cg, 8-output-row tile ohT). Reads 17 input
// rows (halo 17/16 = 1.06x, x is L3-resident after K1). Norm rows + 520 weight
// sets staged in LDS once; then one output per thread-task, verified math.
#define R       8              // output rows per block
#define CPB     8              // channels per block
#define K2_TPB  256
#define NT      ((OH + R - 1) / R)   // 9
#define NROWS   (2 * R + 1)          // 17 input rows
#define WSETS   (R * OW)             // 520

__global__ __launch_bounds__(K2_TPB) void pool_kernel(const float* __restrict__ x,
                                                      const float* __restrict__ nrm,
                                                      float* __restrict__ out) {
    const int ohT = blockIdx.x;
    const int cg  = blockIdx.y;
    const int b   = blockIdx.z;
    const int oh0 = ohT * R;
    const int tid = threadIdx.x;

    __shared__ float ns[NROWS][W];     // 8.7 KB: clamped norm rows
    __shared__ float wls[WSETS][9];    // 18.7 KB: softmax weights (stride 9 = odd)

    // stage norm rows (clamped; validity handled by weight masking)
    for (int id = tid; id < NROWS * W; id += K2_TPB) {
        int r = id >> 7, col = id & (W - 1);
        int ih  = oh0 * 2 - 2 + r;
        int ihc = ih < 0 ? 0 : (ih > H - 1 ? H - 1 : ih);
        ns[r][col] = nrm[(size_t)b * HW + ihc * W + col];
    }
    __syncthreads();

    // 520 softmax weight sets (verified math; OOB -> nv=0 in denom, wt=0 numer)
    for (int id = tid; id < WSETS; id += K2_TPB) {
        int ohl = id / OW;
        int ow  = id - ohl * OW;
        int oh  = oh0 + ohl;
        if (oh < OH) {
            int iw0 = ow * 2 - 2;
            float nv[9]; bool val[9]; float m = 0.0f;
            #pragma unroll
            for (int kh = 0; kh < 3; ++kh) {
                int ih = oh * 2 + kh - 2;
                bool vh = (unsigned)ih < (unsigned)H;
                int rL = 2 * ohl + kh;           // local norm row
                #pragma unroll
                for (int kw = 0; kw < 3; ++kw) {
                    int iw = iw0 + kw;
                    int k  = kh * 3 + kw;
                    bool v = vh && ((unsigned)iw < (unsigned)W);
                    val[k] = v;
                    nv[k]  = v ? ns[rL][iw] : 0.0f;
                    m = fmaxf(m, nv[k]);
                }
            }
            float denom = 0.0f, wt[9];
            #pragma unroll
            for (int k = 0; k < 9; ++k) {
                float e = __expf(nv[k] - m);
                denom += e;
                wt[k] = val[k] ? e : 0.0f;
            }
            float inv = 1.0f / denom;
            #pragma unroll
            for (int k = 0; k < 9; ++k) wls[id][k] = wt[k] * inv;
        }
    }
    __syncthreads();

    // pooling: 8 ch x 8 rows x 65 cols = 4160 outputs, one per thread-task
    const float* xg = x + (size_t)(b * CH + cg * CPB) * HW;
    float*       og = out + (size_t)(b * CH + cg * CPB) * NPIX;
    for (int id = tid; id < CPB * WSETS; id += K2_TPB) {
        int c   = id / WSETS;
        int rem = id - c * WSETS;
        int ohl = rem / OW;
        int ow  = rem - ohl * OW;
        int oh  = oh0 + ohl;
        if (oh >= OH) continue;
        int iw0 = ow * 2 - 2;
        int iwa = iw0 < 0 ? 0 : iw0;                       // even -> aligned float2
        int iwc = (iw0 + 2) > (W - 1) ? (W - 1) : (iw0 + 2);
        const float* xc = xg + (size_t)c * HW;
        float acc = 0.f;
        #pragma unroll
        for (int r = 0; r < 3; ++r) {
            int ih  = oh * 2 + r - 2;
            int ihc = ih < 0 ? 0 : (ih > H - 1 ? H - 1 : ih);
            float2 v2 = *(const float2*)(xc + ihc * W + iwa);
            float  vs = xc[ihc * W + iwc];
            acc += wls[rem][r * 3 + 0] * v2.x
                 + wls[rem][r * 3 + 1] * v2.y
                 + wls[rem][r * 3 + 2] * vs;
        }
        og[(size_t)c * NPIX + oh * OW + ow] = acc;
    }
}

extern "C" void kernel_launch(void* const* d_in, const int* in_sizes, int n_in,
                              void* d_out, int out_size, void* d_ws, size_t ws_size,
                              hipStream_t stream) {
    const float* x = (const float*)d_in[0];
    float* out  = (float*)d_out;
    float* nbuf = (float*)d_ws;   // BATCH*H*W floats = 512 KB

    norm_kernel<<<BATCH * (HW / NTILE), K1_TPB, 0, stream>>>((const float4*)x, nbuf);

    dim3 grid(NT, CH / CPB, BATCH);   // 9 x 32 x 8 = 2304 blocks
    pool_kernel<<<grid, K2_TPB, 0, stream>>>(x, nbuf, out);
}

// Round 6
// 224.128 us; speedup vs baseline: 1.0376x; 1.0376x over previous
//
#include <hip/hip_runtime.h>
#include <math.h>

#define BATCH 8
#define CH    256
#define H     128
#define W     128
#define HW    (H * W)          // 16384
#define OH    65
#define OW    65
#define NPIX  (OH * OW)        // 4225

// ---------------- K1: channel L2 norms, pure stream ----------------
// 512 blocks (2/CU) x 256 thr (4 waves). Block = 256-pixel tile of one image;
// wave wv covers channels [wv*64, wv*64+64). Per channel the wave reads
// 64 float4 = 1 KB contiguous; 64 independent loads/lane -> deep pipeline.
__global__ __launch_bounds__(256) void norm_kernel(const float4* __restrict__ x4,
                                                   float* __restrict__ nrm) {
    const int b    = blockIdx.x >> 6;      // 0..7
    const int t    = blockIdx.x & 63;      // 256-px tile within image
    const int lane = threadIdx.x & 63;
    const int wv   = threadIdx.x >> 6;     // 0..3

    const float4* p = x4 + (size_t)(b * CH + wv * 64) * (HW / 4) + t * 64 + lane;
    float4 a = {0.f, 0.f, 0.f, 0.f};
    #pragma unroll 8
    for (int c = 0; c < 64; ++c) {
        float4 v = p[(size_t)c * (HW / 4)];
        a.x += v.x * v.x; a.y += v.y * v.y;
        a.z += v.z * v.z; a.w += v.w * v.w;
    }
    __shared__ float part[4][256];
    ((float4*)part[wv])[lane] = a;         // flat px index = 4*lane+comp
    __syncthreads();
    float s = part[0][threadIdx.x] + part[1][threadIdx.x]
            + part[2][threadIdx.x] + part[3][threadIdx.x];
    nrm[(size_t)b * HW + t * 256 + threadIdx.x] = sqrtf(s);
}

// ---------------- K2: softmax-weighted 3x3/s2 pool, 2 output rows/block ----
// Block = (image b, output-row pair oh0=2*ohT). Reads 5 clamped input rows ->
// 1.27x vertical amplification (vs 3x when 1 row/block). 8 waves x 32 ch,
// lane l owns input cols (2l, 2l+1); verified S/T shuffle decomposition:
//   out[ow] = T_ow + S_{ow-1};  out[0]=T_0 (OOB weights are 0);  out[64]=S_63.
#define OHT   33               // ceil(OH/2) row-pairs per image
#define K2TPB 512
#define CPW   32

__global__ __launch_bounds__(K2TPB) void pool_kernel(const float* __restrict__ x,
                                                     const float* __restrict__ nrm,
                                                     float* __restrict__ out) {
    // b = bid & 7 pins each image to one XCD; adjacent row-pair blocks (which
    // share the boundary input row) are bid+-8 -> same XCD L2.
    const int b    = blockIdx.x & 7;
    const int ohT  = blockIdx.x >> 3;      // 0..32
    const int oh0  = ohT * 2;
    const bool hasB = (oh0 + 1) < OH;      // last block has only row A
    const int tid  = threadIdx.x;
    const int lane = tid & 63;
    const int wv   = tid >> 6;

    // 5 clamped input rows rows ih = 2*oh0-2+r  (A uses r=0..2, B uses r=2..4)
    int rowc[5];
    #pragma unroll
    for (int r = 0; r < 5; ++r) {
        int ih = oh0 * 2 - 2 + r;
        rowc[r] = ih < 0 ? 0 : (ih > H - 1 ? H - 1 : ih);
    }

    __shared__ float ns[5][W];       // 2.5 KB clamped norm rows
    __shared__ float wls[2 * OH][9]; // 4.6 KB weights: rows [0,65)=A, [65,130)=B

    // stage norm rows (640 values)
    for (int id = tid; id < 5 * W; id += K2TPB) {
        int r = id >> 7, col = id & (W - 1);
        ns[r][col] = nrm[(size_t)b * HW + rowc[r] * W + col];
    }
    __syncthreads();

    // 130 softmax weight sets (verified math; OOB -> nv=0 in denom, wt=0 numer)
    if (tid < 2 * OH) {
        int ohl = tid >= OH ? 1 : 0;
        int ow  = tid - ohl * OH;
        int oh  = oh0 + ohl;
        if (oh < OH) {
            int iw0 = ow * 2 - 2;
            float nv[9]; bool val[9]; float m = 0.0f;
            #pragma unroll
            for (int kh = 0; kh < 3; ++kh) {
                int ih = oh * 2 + kh - 2;
                bool vh = (unsigned)ih < (unsigned)H;
                int rL = 2 * ohl + kh;               // local ns row
                #pragma unroll
                for (int kw = 0; kw < 3; ++kw) {
                    int iw = iw0 + kw;
                    int k  = kh * 3 + kw;
                    bool v = vh && ((unsigned)iw < (unsigned)W);
                    val[k] = v;
                    nv[k]  = v ? ns[rL][iw] : 0.0f;
                    m = fmaxf(m, nv[k]);
                }
            }
            float denom = 0.0f, wt[9];
            #pragma unroll
            for (int k = 0; k < 9; ++k) {
                float e = __expf(nv[k] - m);
                denom += e;
                wt[k] = val[k] ? e : 0.0f;
            }
            float inv = 1.0f / denom;
            #pragma unroll
            for (int k = 0; k < 9; ++k) wls[tid][k] = wt[k] * inv;
        }
    }
    __syncthreads();

    // per-lane weights (distinct rows, stride 9 -> <=2-way bank alias = free)
    const float aA0 = wls[lane][2],     aA1 = wls[lane][5],     aA2 = wls[lane][8];
    const float aB0 = wls[lane + 1][0], aC0 = wls[lane + 1][1];
    const float aB1 = wls[lane + 1][3], aC1 = wls[lane + 1][4];
    const float aB2 = wls[lane + 1][6], aC2 = wls[lane + 1][7];
    const float bA0 = wls[OH + lane][2],     bA1 = wls[OH + lane][5],     bA2 = wls[OH + lane][8];
    const float bB0 = wls[OH + lane + 1][0], bC0 = wls[OH + lane + 1][1];
    const float bB1 = wls[OH + lane + 1][3], bC1 = wls[OH + lane + 1][4];
    const float bB2 = wls[OH + lane + 1][6], bC2 = wls[OH + lane + 1][7];

    const float2* xw2 = (const float2*)x + (size_t)(b * CH + wv * CPW) * (HW / 2);
    const int base0 = rowc[0] * (W / 2) + lane;
    const int base1 = rowc[1] * (W / 2) + lane;
    const int base2 = rowc[2] * (W / 2) + lane;
    const int base3 = rowc[3] * (W / 2) + lane;
    const int base4 = rowc[4] * (W / 2) + lane;

    float* ob = out + (size_t)(b * CH + wv * CPW) * NPIX + (size_t)oh0 * OW;
    #pragma unroll 4
    for (int c = 0; c < CPW; ++c) {
        const size_t cb = (size_t)c * (HW / 2);
        float2 v0 = xw2[cb + base0];
        float2 v1 = xw2[cb + base1];
        float2 v2 = xw2[cb + base2];
        // row A (oh0): window rows 0,1,2
        float SA = aB0 * v0.x + aC0 * v0.y
                 + aB1 * v1.x + aC1 * v1.y
                 + aB2 * v2.x + aC2 * v2.y;          // -> out[lane+1]
        float TA = aA0 * v0.x + aA1 * v1.x + aA2 * v2.x;
        float SpA = __shfl_up(SA, 1);
        float resA = (lane == 0) ? TA : TA + SpA;
        float* oc = ob + (size_t)c * NPIX;
        oc[lane] = resA;
        if (lane == 63) oc[64] = SA;                 // ow=64: kw=2 weight is 0
        if (hasB) {
            float2 v3 = xw2[cb + base3];
            float2 v4 = xw2[cb + base4];
            // row B (oh0+1): window rows 2,3,4
            float SB = bB0 * v2.x + bC0 * v2.y
                     + bB1 * v3.x + bC1 * v3.y
                     + bB2 * v4.x + bC2 * v4.y;
            float TB = bA0 * v2.x + bA1 * v3.x + bA2 * v4.x;
            float SpB = __shfl_up(SB, 1);
            float resB = (lane == 0) ? TB : TB + SpB;
            oc[OW + lane] = resB;
            if (lane == 63) oc[OW + 64] = SB;
        }
    }
}

extern "C" void kernel_launch(void* const* d_in, const int* in_sizes, int n_in,
                              void* d_out, int out_size, void* d_ws, size_t ws_size,
                              hipStream_t stream) {
    const float* x = (const float*)d_in[0];
    float* out  = (float*)d_out;
    float* nbuf = (float*)d_ws;   // BATCH*H*W floats = 512 KB

    norm_kernel<<<512, 256, 0, stream>>>((const float4*)x, nbuf);
    // 33 row-pair tiles * 8 images = 264 blocks (div by 8 -> clean XCD pinning)
    pool_kernel<<<BATCH * OHT, K2TPB, 0, stream>>>(x, nbuf, out);
}

// Round 7
// 218.637 us; speedup vs baseline: 1.0637x; 1.0251x over previous
//
#include <hip/hip_runtime.h>
#include <math.h>

#define BATCH 8
#define CH    256
#define H     128
#define W     128
#define HW    (H * W)          // 16384
#define OH    65
#define OW    65
#define NPIX  (OH * OW)        // 4225

// ---------------- K1: channel L2 norms, pure stream ----------------
// 512 blocks (2/CU) x 256 thr (4 waves). Block = 256-pixel tile of one image;
// wave wv covers channels [wv*64, wv*64+64). Per channel the wave reads
// 1 KB contiguous; 64 independent loads/lane -> deep pipeline. Primes L3 with x.
__global__ __launch_bounds__(256) void norm_kernel(const float4* __restrict__ x4,
                                                   float* __restrict__ nrm) {
    const int b    = blockIdx.x >> 6;      // 0..7
    const int t    = blockIdx.x & 63;      // 256-px tile within image
    const int lane = threadIdx.x & 63;
    const int wv   = threadIdx.x >> 6;     // 0..3

    const float4* p = x4 + (size_t)(b * CH + wv * 64) * (HW / 4) + t * 64 + lane;
    float4 a = {0.f, 0.f, 0.f, 0.f};
    #pragma unroll 8
    for (int c = 0; c < 64; ++c) {
        float4 v = p[(size_t)c * (HW / 4)];
        a.x += v.x * v.x; a.y += v.y * v.y;
        a.z += v.z * v.z; a.w += v.w * v.w;
    }
    __shared__ float part[4][256];
    ((float4*)part[wv])[lane] = a;         // flat px index = 4*lane+comp
    __syncthreads();
    float s = part[0][threadIdx.x] + part[1][threadIdx.x]
            + part[2][threadIdx.x] + part[3][threadIdx.x];
    nrm[(size_t)b * HW + t * 256 + threadIdx.x] = sqrtf(s);
}

// ---------------- K2: softmax-weighted 3x3/s2 pool ----------------
// One output row per block, channels split in half: grid = 8*65*2 = 1040
// blocks x 256 thr (4 waves x 32 ch). Small blocks + tiny LDS -> ~4 blocks/CU
// resident: barriers and the weight phase are covered by other blocks.
// Verified S/T shuffle decomposition: lane l owns input cols (2l, 2l+1);
//   out[ow] = T_ow + S_{ow-1};  out[0] = T_0;  out[64] = S_63 (kw=2 wt is 0).
#define K2TPB 256
#define CPW   32               // channels per wave
#define CGC   128              // channels per block (half)

__global__ __launch_bounds__(K2TPB) void pool_kernel(const float* __restrict__ x,
                                                     const float* __restrict__ nrm,
                                                     float* __restrict__ out) {
    // b = bid & 7 pins each image to one XCD; blocks on one XCD step through
    // consecutive oh for fixed (cg, b) -> shared halo rows stay L2-local.
    const int b   = blockIdx.x & 7;
    const int rem = blockIdx.x >> 3;       // 0..129
    const int oh  = rem % OH;
    const int cg  = rem / OH;              // 0 or 1
    const int tid  = threadIdx.x;
    const int lane = tid & 63;
    const int wv   = tid >> 6;

    // clamped input rows for this output row (block-uniform)
    int  rowc[3];
    #pragma unroll
    for (int r = 0; r < 3; ++r) {
        int ih = oh * 2 + r - 2;
        rowc[r] = ih < 0 ? 0 : (ih > H - 1 ? H - 1 : ih);
    }

    __shared__ float ns[3][W];       // 1.5 KB clamped norm rows
    __shared__ float wls[OH][9];     // 2.3 KB softmax weights (stride 9 = odd)

    // stage the 3 norm rows (384 values, coalesced)
    for (int id = tid; id < 3 * W; id += K2TPB) {
        int r = id >> 7, col = id & (W - 1);
        ns[r][col] = nrm[(size_t)b * HW + rowc[r] * W + col];
    }
    __syncthreads();

    // 65 softmax weight sets (verified math; OOB -> nv=0 in denom, wt=0 numer)
    if (tid < OH) {
        const int ow  = tid;
        const int iw0 = ow * 2 - 2;
        float nv[9]; bool val[9]; float m = 0.0f;
        #pragma unroll
        for (int kh = 0; kh < 3; ++kh) {
            int ih = oh * 2 + kh - 2;
            bool vh = (unsigned)ih < (unsigned)H;
            #pragma unroll
            for (int kw = 0; kw < 3; ++kw) {
                int iw = iw0 + kw;
                int k  = kh * 3 + kw;
                bool v = vh && ((unsigned)iw < (unsigned)W);
                val[k] = v;
                nv[k]  = v ? ns[kh][iw] : 0.0f;
                m = fmaxf(m, nv[k]);
            }
        }
        float denom = 0.0f, wt[9];
        #pragma unroll
        for (int k = 0; k < 9; ++k) {
            float e = __expf(nv[k] - m);
            denom += e;
            wt[k] = val[k] ? e : 0.0f;
        }
        float inv = 1.0f / denom;
        #pragma unroll
        for (int k = 0; k < 9; ++k) wls[ow][k] = wt[k] * inv;
    }
    __syncthreads();

    // per-lane weights (distinct rows, stride 9 -> <=2-way bank alias = free)
    const float wA0 = wls[lane][2], wA1 = wls[lane][5], wA2 = wls[lane][8];
    const float wB0 = wls[lane + 1][0], wC0 = wls[lane + 1][1];
    const float wB1 = wls[lane + 1][3], wC1 = wls[lane + 1][4];
    const float wB2 = wls[lane + 1][6], wC2 = wls[lane + 1][7];

    const float2* xw2 = (const float2*)x
        + (size_t)(b * CH + cg * CGC + wv * CPW) * (HW / 2);
    const int base0 = rowc[0] * (W / 2) + lane;
    const int base1 = rowc[1] * (W / 2) + lane;
    const int base2 = rowc[2] * (W / 2) + lane;

    float* ob = out + (size_t)(b * CH + cg * CGC + wv * CPW) * NPIX
                    + (size_t)oh * OW;
    #pragma unroll 8
    for (int c = 0; c < CPW; ++c) {
        const size_t cb = (size_t)c * (HW / 2);
        float2 v0 = xw2[cb + base0];
        float2 v1 = xw2[cb + base1];
        float2 v2 = xw2[cb + base2];
        float S = wB0 * v0.x + wC0 * v0.y
                + wB1 * v1.x + wC1 * v1.y
                + wB2 * v2.x + wC2 * v2.y;            // -> out[lane+1]
        float T = wA0 * v0.x + wA1 * v1.x + wA2 * v2.x;  // -> out[lane]
        float Sp = __shfl_up(S, 1);
        float res = (lane == 0) ? T : T + Sp;
        float* oc = ob + (size_t)c * NPIX;
        oc[lane] = res;                                // coalesced 64-float run
        if (lane == 63) oc[64] = S;                    // ow=64
    }
}

extern "C" void kernel_launch(void* const* d_in, const int* in_sizes, int n_in,
                              void* d_out, int out_size, void* d_ws, size_t ws_size,
                              hipStream_t stream) {
    const float* x = (const float*)d_in[0];
    float* out  = (float*)d_out;
    float* nbuf = (float*)d_ws;   // BATCH*H*W floats = 512 KB

    norm_kernel<<<512, 256, 0, stream>>>((const float4*)x, nbuf);
    // 8 images * 65 rows * 2 channel-halves = 1040 blocks (div by 8 -> XCD pin)
    pool_kernel<<<BATCH * OH * 2, K2TPB, 0, stream>>>(x, nbuf, out);
}